// Round 4
// baseline (119.685 us; speedup 1.0000x reference)
//
#include <hip/hip_runtime.h>
#include <hip/hip_fp16.h>

// Problem constants (from reference) — ALL TENSORS ARE FLOAT32.
#define B_    1024
#define N_    256
#define E_    2304      // == 9 * 256 exactly
#define EPT_  9         // edges per thread in CSR build
#define EP_   3072      // padded edge capacity: per-node segs rounded up to 4
#define FIN_  6
#define VEC_  26
#define HSTR_ 40        // f16 LDS row stride (80 B, 16B-aligned)

typedef _Float16 half8 __attribute__((ext_vector_type(8)));
typedef float    f32x4 __attribute__((ext_vector_type(4)));

// ---------------------------------------------------------------------------
// One block per batch (1024 blocks, 4/CU, 16 waves/CU). Round-3 post-mortem:
// kernel is LATENCY-bound (VALUBusy 18%, occ 20%, HBM 2%) — the per-edge
// dependent LDS chain (packedE read -> row reads) was the critical path.
// Fixes: (a) per-node edge segments padded to multiples of 4 so the gather
// consumes 4 edges per ds_read_b128 with independent row loads in flight,
// (b) next-quad prefetch, (c) feature row prefetched into registers at kernel
// entry (HBM latency hides under CSR build), (d) occupancy back to 4 blk/CU.
// ---------------------------------------------------------------------------
__global__ __launch_bounds__(256, 4) void fused_kernel(
    const float* __restrict__ gf,    // [B,N,6]
    const float* __restrict__ vec,   // [B,26]
    const int* __restrict__ src, const int* __restrict__ dst,
    const float* __restrict__ W1, const float* __restrict__ b1,   // [6,32],[32]
    const float* __restrict__ W2, const float* __restrict__ b2,   // [32,32]
    const float* __restrict__ W3, const float* __restrict__ b3,
    const float* __restrict__ We, const float* __restrict__ be,   // [32,32]
    const float* __restrict__ Wpi, const float* __restrict__ bpi, // [58,512],[512]
    const float* __restrict__ Wvf, const float* __restrict__ bvf,
    float2* __restrict__ out)        // f32 pairs; pi @ [0,262144), vf @ +262144
{
    __shared__ __align__(16) __half hbuf[N_ * HSTR_];        // 20,480 B
    __shared__ __align__(16) unsigned int packedE[EP_];      // 12,288 B
    __shared__ float part[8 * 33];
    __shared__ float hgl[32];
    __shared__ float comb[VEC_ + 32];
    __shared__ int   wsum[4];

    const int t = threadIdx.x;
    const int b = blockIdx.x;
    const int lane = t & 63, wv = t >> 6;

    // ---- early global prefetch: this thread's feature row (24 B, 8B-aligned)
    // consumed only after the CSR build -> HBM latency fully hidden.
    const float* gft = gf + (size_t)b * (N_ * FIN_) + t * FIN_;
    const float2 f01 = *(const float2*)(gft);
    const float2 f23 = *(const float2*)(gft + 2);
    const float2 f45 = *(const float2*)(gft + 4);

    // ---- CSR scratch overlaid on hbuf (consumed before feature staging) ----
    int*   deg_o  = (int*)hbuf;          // [256]
    int*   deg_i  = (int*)hbuf + 256;    // [256]
    int*   scanA  = (int*)hbuf + 512;    // [256] inclusive scan of degP (padded)
    int*   cursor = (int*)hbuf + 768;    // [256]
    int*   perm   = (int*)hbuf + 1024;   // [256]
    float* inv_o  = (float*)hbuf + 1280; // [256]
    float* inv_i  = (float*)hbuf + 1536; // [256]
    int*   bcnt   = (int*)hbuf + 1792;   // [64]
    int*   boff   = (int*)hbuf + 1856;   // [64]

    // 1. zero counters
    deg_o[t] = 0; deg_i[t] = 0;
    if (t < 64) bcnt[t] = 0;
    __syncthreads();

    // 2. load edges, count degrees
    int sB[EPT_], dB[EPT_];
#pragma unroll
    for (int i = 0; i < EPT_; ++i) { int e = t + 256 * i; sB[i] = src[e]; dB[i] = dst[e]; }
#pragma unroll
    for (int i = 0; i < EPT_; ++i) { atomicAdd(&deg_o[sB[i]], 1); atomicAdd(&deg_i[dB[i]], 1); }
    __syncthreads();

    // 3. inv factors + wave-level scan of PADDED deg (degP = ceil4(deg_i))
    const int dI = deg_i[t];
    const int dP = (dI + 3) & ~3;
    {
        int dO = deg_o[t];
        inv_o[t] = dO > 0 ? rsqrtf((float)dO) : 0.f;
        inv_i[t] = dI > 0 ? rsqrtf((float)dI) : 0.f;
    }
    int x = dP;
#pragma unroll
    for (int d = 1; d < 64; d <<= 1) {
        int y = __shfl_up(x, d, 64);
        if (lane >= d) x += y;
    }
    if (lane == 63) wsum[wv] = x;
    const int bucket = dI > 63 ? 63 : dI;
    atomicAdd(&bcnt[bucket], 1);
    __syncthreads();

    // 4. combine wave sums; bucket-offset scan (wave 0)
    {
        int prefix = 0;
#pragma unroll
        for (int w = 0; w < 3; ++w) if (w < wv) prefix += wsum[w];
        int incl = x + prefix;
        scanA[t]  = incl;          // segment end (exclusive), padded space
        cursor[t] = incl - dP;     // segment base (4-aligned)
    }
    if (t < 64) {
        int c = bcnt[t], xx = c;
#pragma unroll
        for (int d = 1; d < 64; d <<= 1) {
            int y = __shfl_up(xx, d, 64);
            if (lane >= d) xx += y;
        }
        boff[t] = xx - c;   // exclusive
    }
    __syncthreads();

    // 5. degree-sorted perm scatter + edge scatter + pad fill (zero-weight)
    { int pos = atomicAdd(&boff[bucket], 1); perm[pos] = t; }
#pragma unroll
    for (int i = 0; i < EPT_; ++i) {
        int s = sB[i], dd = dB[i];
        int pos = atomicAdd(&cursor[dd], 1);
        float nrm = inv_o[s] * inv_i[dd];
        unsigned short h = __half_as_ushort(__float2half(nrm));
        packedE[pos] = ((unsigned int)s << 16) | (unsigned int)h;
    }
    {   // pads [base+dI, base+dP) for node t: src=0, w=+0.0 -> exact no-op edges
        int e0 = scanA[t] - dP + dI, e1 = scanA[t];
        for (int p = e0; p < e1; ++p) packedE[p] = 0u;
    }
    __syncthreads();

    // 6. node assignment into registers; then overlay is dead
    const int node = perm[t];
    const int dIn  = deg_i[node];
    const int end  = scanA[node];
    const int beg  = end - ((dIn + 3) & ~3);   // 4-aligned
    __syncthreads();

    // ---- stage node features (from prefetched regs; cols 6,7 zero-pad) ----
    {
        union { float4 f4; __half2 h2[4]; } w;
        w.h2[0] = __floats2half2_rn(f01.x, f01.y);
        w.h2[1] = __floats2half2_rn(f23.x, f23.y);
        w.h2[2] = __floats2half2_rn(f45.x, f45.y);
        w.h2[3] = __floats2half2_rn(0.f, 0.f);
        *(float4*)&hbuf[t * HSTR_] = w.f4;   // features of node t live in row t
    }
    __syncthreads();

    const __half2 z2 = __float2half2_rn(0.f);

    // ---- layer 1: quad-edge f16 gather + f32 [6x32] GEMM + relu ----
    {
        __half2 a2[4] = {z2, z2, z2, z2};
#define L1_EDGE(U) { \
        __half2 w2 = __half2half2(__ushort_as_half((unsigned short)((U) & 0xffffu))); \
        union { float4 f4; __half2 h2[4]; } r; \
        r.f4 = *(const float4*)&hbuf[((U) >> 16) * HSTR_]; \
        a2[0] = __hfma2(w2, r.h2[0], a2[0]); a2[1] = __hfma2(w2, r.h2[1], a2[1]); \
        a2[2] = __hfma2(w2, r.h2[2], a2[2]); a2[3] = __hfma2(w2, r.h2[3], a2[3]); }
        uint4 uu = *(const uint4*)&packedE[beg];
        for (int e = beg; e < end; e += 4) {
            uint4 uun = uu;
            if (e + 4 < end) uun = *(const uint4*)&packedE[e + 4];
            L1_EDGE(uu.x); L1_EDGE(uu.y); L1_EDGE(uu.z); L1_EDGE(uu.w);
            uu = uun;
        }
#undef L1_EDGE
        float a[FIN_], o[32];
#pragma unroll
        for (int k = 0; k < FIN_; ++k)
            a[k] = (k & 1) ? __high2float(a2[k >> 1]) : __low2float(a2[k >> 1]);
#pragma unroll
        for (int j = 0; j < 32; ++j) o[j] = b1[j];
#pragma unroll
        for (int k = 0; k < FIN_; ++k) {
            float ak = a[k];
            const float* wr = &W1[k * 32];
#pragma unroll
            for (int j = 0; j < 32; ++j) o[j] += ak * wr[j];
        }
        __syncthreads();
        union { float4 f4; __half2 h2[4]; } w;
        float4* row = (float4*)&hbuf[node * HSTR_];
#pragma unroll
        for (int q = 0; q < 4; ++q) {
#pragma unroll
            for (int r = 0; r < 4; ++r)
                w.h2[r] = __floats2half2_rn(fmaxf(o[8*q + 2*r], 0.f), fmaxf(o[8*q + 2*r + 1], 0.f));
            row[q] = w.f4;
        }
    }
    __syncthreads();

    // ---- layers 2 & 3: quad-edge f16 gather + MFMA 16x16x32 GEMM ----
    const int m16  = lane & 15;       // MFMA row/col-within-16
    const int q4   = lane >> 4;       // quad index 0..3
    const int slab = wv * 64;         // this wave's private 64-node slab

    for (int L = 0; L < 2; ++L) {
        const float* Wl = (L == 0) ? W2 : W3;
        const float* Bl = (L == 0) ? b2 : b3;

        // prefetch B fragments + bias (global, overlaps gather below)
        half8 bfrag[2];
        float bias_c[2];
#pragma unroll
        for (int h = 0; h < 2; ++h) {
            int col = m16 + 16 * h;
#pragma unroll
            for (int j = 0; j < 8; ++j)
                bfrag[h][j] = (_Float16)Wl[(q4 * 8 + j) * 32 + col];
            bias_c[h] = Bl[col];
        }

        // gather: acc2 = sum_e w * h[src], 4 edges per packedE b128 read
        __half2 acc2[16];
#pragma unroll
        for (int j = 0; j < 16; ++j) acc2[j] = z2;
#define L23_EDGE(U) { \
        __half2 w2 = __half2half2(__ushort_as_half((unsigned short)((U) & 0xffffu))); \
        const float4* hr = (const float4*)&hbuf[((U) >> 16) * HSTR_]; \
        union { float4 f4; __half2 h2[4]; } r0, r1, r2, r3; \
        r0.f4 = hr[0]; r1.f4 = hr[1]; r2.f4 = hr[2]; r3.f4 = hr[3]; \
        acc2[0]  = __hfma2(w2, r0.h2[0], acc2[0]);  acc2[1]  = __hfma2(w2, r0.h2[1], acc2[1]); \
        acc2[2]  = __hfma2(w2, r0.h2[2], acc2[2]);  acc2[3]  = __hfma2(w2, r0.h2[3], acc2[3]); \
        acc2[4]  = __hfma2(w2, r1.h2[0], acc2[4]);  acc2[5]  = __hfma2(w2, r1.h2[1], acc2[5]); \
        acc2[6]  = __hfma2(w2, r1.h2[2], acc2[6]);  acc2[7]  = __hfma2(w2, r1.h2[3], acc2[7]); \
        acc2[8]  = __hfma2(w2, r2.h2[0], acc2[8]);  acc2[9]  = __hfma2(w2, r2.h2[1], acc2[9]); \
        acc2[10] = __hfma2(w2, r2.h2[2], acc2[10]); acc2[11] = __hfma2(w2, r2.h2[3], acc2[11]); \
        acc2[12] = __hfma2(w2, r3.h2[0], acc2[12]); acc2[13] = __hfma2(w2, r3.h2[1], acc2[13]); \
        acc2[14] = __hfma2(w2, r3.h2[2], acc2[14]); acc2[15] = __hfma2(w2, r3.h2[3], acc2[15]); }
        uint4 uu = *(const uint4*)&packedE[beg];
        for (int e = beg; e < end; e += 4) {
            uint4 uun = uu;
            if (e + 4 < end) uun = *(const uint4*)&packedE[e + 4];
            L23_EDGE(uu.x); L23_EDGE(uu.y); L23_EDGE(uu.z); L23_EDGE(uu.w);
            uu = uun;
        }
#undef L23_EDGE
        __syncthreads();                     // all gather reads of h done
        {
            // stage agg rows into hbuf (h is dead now)
            union { float4 f4; __half2 h2[4]; } w;
            float4* row = (float4*)&hbuf[node * HSTR_];
#pragma unroll
            for (int q = 0; q < 4; ++q) {
#pragma unroll
                for (int r = 0; r < 4; ++r) w.h2[r] = acc2[4 * q + r];
                row[q] = w.f4;
            }
        }
        __syncthreads();                     // agg visible to all

        // MFMA: wave processes its own 64-node slab (no cross-wave hazard)
        half8 afrag[4];
#pragma unroll
        for (int g = 0; g < 4; ++g) {
            union { float4 f4; half8 h8; } u;
            u.f4 = *(const float4*)&hbuf[(slab + g * 16 + m16) * HSTR_ + q4 * 8];
            afrag[g] = u.h8;
        }
        f32x4 D[4][2];
#pragma unroll
        for (int g = 0; g < 4; ++g) {
#pragma unroll
            for (int h = 0; h < 2; ++h) {
                f32x4 c = {bias_c[h], bias_c[h], bias_c[h], bias_c[h]};
                D[g][h] = __builtin_amdgcn_mfma_f32_16x16x32_f16(afrag[g], bfrag[h], c, 0, 0, 0);
            }
        }
        // relu + writeback: D row = q4*4 + r, col = h*16+m16
#pragma unroll
        for (int g = 0; g < 4; ++g) {
#pragma unroll
            for (int h = 0; h < 2; ++h) {
#pragma unroll
                for (int r = 0; r < 4; ++r) {
                    float v = fmaxf(D[g][h][r], 0.f);
                    hbuf[(slab + g * 16 + q4 * 4 + r) * HSTR_ + h * 16 + m16] = __float2half(v);
                }
            }
        }
        __syncthreads();
    }

    // ---- mean over nodes -> hg[32] (f32) ----
    {
        int j = t & 31, g8 = t >> 5;
        float s = 0.f;
        for (int i = 0; i < 32; ++i)
            s += __half2float(hbuf[(g8 * 32 + i) * HSTR_ + j]);
        part[g8 * 33 + j] = s;
    }
    __syncthreads();
    if (t < 32) {
        float sum = 0.f;
#pragma unroll
        for (int g8 = 0; g8 < 8; ++g8) sum += part[g8 * 33 + t];
        hgl[t] = sum * (1.0f / 256.0f);
    }
    __syncthreads();

    // ---- emb + comb (f32) ----
    if (t < 32) {
        float v = be[t];
#pragma unroll
        for (int j = 0; j < 32; ++j) v += hgl[j] * We[j * 32 + t];
        comb[VEC_ + t] = v;
    }
    if (t < VEC_) comb[t] = vec[b * VEC_ + t];
    __syncthreads();

    // ---- head: thread t -> pi/vf outputs 2t, 2t+1 (f32) ----
    {
        float p0 = bpi[2 * t], p1 = bpi[2 * t + 1];
        float v0 = bvf[2 * t], v1 = bvf[2 * t + 1];
        const float2* Wp = (const float2*)Wpi;   // [58][256] float2
        const float2* Wv = (const float2*)Wvf;
#pragma unroll 2
        for (int k = 0; k < VEC_ + 32; ++k) {
            float c = comb[k];
            float2 a = Wp[k * 256 + t];
            p0 += c * a.x; p1 += c * a.y;
            float2 d = Wv[k * 256 + t];
            v0 += c * d.x; v1 += c * d.y;
        }
        out[b * 256 + t]          = make_float2(fmaxf(p0, 0.f), fmaxf(p1, 0.f));
        out[262144 + b * 256 + t] = make_float2(fmaxf(v0, 0.f), fmaxf(v1, 0.f));
    }
}

extern "C" void kernel_launch(void* const* d_in, const int* in_sizes, int n_in,
                              void* d_out, int out_size, void* d_ws, size_t ws_size,
                              hipStream_t stream)
{
    // d_in order: 0 gf, 1 vec, 2 src, 3 dst, 4 W1, 5 b1, 6 W2, 7 b2, 8 W3, 9 b3,
    //             10 W_emb, 11 b_emb, 12 W_pi, 13 b_pi, 14 W_vf, 15 b_vf
    fused_kernel<<<B_, 256, 0, stream>>>(
        (const float*)d_in[0], (const float*)d_in[1],
        (const int*)d_in[2], (const int*)d_in[3],
        (const float*)d_in[4], (const float*)d_in[5],
        (const float*)d_in[6], (const float*)d_in[7],
        (const float*)d_in[8], (const float*)d_in[9],
        (const float*)d_in[10], (const float*)d_in[11],
        (const float*)d_in[12], (const float*)d_in[13],
        (const float*)d_in[14], (const float*)d_in[15],
        (float2*)d_out);
}

// Round 8
// 117.660 us; speedup vs baseline: 1.0172x; 1.0172x over previous
//
#include <hip/hip_runtime.h>
#include <hip/hip_fp16.h>

// Problem constants (from reference) — ALL TENSORS ARE FLOAT32.
#define B_    1024
#define N_    256
#define E_    2304      // == 9 * 256 exactly
#define EPT_  9         // edges per thread in CSR build
#define FIN_  6
#define VEC_  26
#define HSTR_ 40        // f16 LDS row stride (80 B, 16B-aligned)
#define BPB_  2         // batches per block (amortize CSR/staging/head)

typedef _Float16 half8 __attribute__((ext_vector_type(8)));
typedef float    f32x4 __attribute__((ext_vector_type(4)));

// ---------------------------------------------------------------------------
// Single fused kernel, 512 blocks x 256 threads; each block = 2 batch elems.
// EXACT resubmission of the round-3 kernel (last known-pass, 117.5 us) as the
// discriminating experiment for the rounds-5..7 tripwire failures: if this
// passes, the hazard is in the rounds-5+ delta (H2); if it fails, the harness
// tripwire got stricter (H1) and the next step is a fully deterministic CSR
// build (no LDS-atomic position assignment).
// ---------------------------------------------------------------------------
__global__ __launch_bounds__(256) void fused_kernel(
    const float* __restrict__ gf,    // [B,N,6]
    const float* __restrict__ vec,   // [B,26]
    const int* __restrict__ src, const int* __restrict__ dst,
    const float* __restrict__ W1, const float* __restrict__ b1,   // [6,32],[32]
    const float* __restrict__ W2, const float* __restrict__ b2,   // [32,32]
    const float* __restrict__ W3, const float* __restrict__ b3,
    const float* __restrict__ We, const float* __restrict__ be,   // [32,32]
    const float* __restrict__ Wpi, const float* __restrict__ bpi, // [58,512],[512]
    const float* __restrict__ Wvf, const float* __restrict__ bvf,
    float2* __restrict__ out)        // f32 pairs; pi @ [0,262144), vf @ +262144
{
    __shared__ __align__(16) __half hbuf[BPB_][N_ * HSTR_];  // 40,960 B
    __shared__ unsigned int packedE[E_];                     //  9,216 B
    __shared__ float part[BPB_][8 * 33];
    __shared__ float hgl[BPB_][32];
    __shared__ float combS[BPB_][64];
    __shared__ int   wsum[4];

    const int t = threadIdx.x;
    const int b0 = blockIdx.x * BPB_;
    const int lane = t & 63, wv = t >> 6;

    // ---- CSR scratch overlaid on hbuf[0] (consumed before feature staging) ----
    int*   deg_o  = (int*)&hbuf[0][0];          // [256]
    int*   deg_i  = (int*)&hbuf[0][0] + 256;    // [256]
    int*   scanA  = (int*)&hbuf[0][0] + 512;    // [256]
    int*   cursor = (int*)&hbuf[0][0] + 768;    // [256]
    int*   perm   = (int*)&hbuf[0][0] + 1024;   // [256]
    float* inv_o  = (float*)&hbuf[0][0] + 1280; // [256]
    float* inv_i  = (float*)&hbuf[0][0] + 1536; // [256]
    int*   bcnt   = (int*)&hbuf[0][0] + 1792;   // [64]
    int*   boff   = (int*)&hbuf[0][0] + 1856;   // [64]

    // 1. zero counters
    deg_o[t] = 0; deg_i[t] = 0;
    if (t < 64) bcnt[t] = 0;
    __syncthreads();

    // 2. load edges, count degrees
    int sB[EPT_], dB[EPT_];
#pragma unroll
    for (int i = 0; i < EPT_; ++i) { int e = t + 256 * i; sB[i] = src[e]; dB[i] = dst[e]; }
#pragma unroll
    for (int i = 0; i < EPT_; ++i) { atomicAdd(&deg_o[sB[i]], 1); atomicAdd(&deg_i[dB[i]], 1); }
    __syncthreads();

    // 3. inv factors + wave-level scan of deg_i + bucket counts
    const int dI = deg_i[t];
    {
        int dO = deg_o[t];
        inv_o[t] = dO > 0 ? rsqrtf((float)dO) : 0.f;
        inv_i[t] = dI > 0 ? rsqrtf((float)dI) : 0.f;
    }
    int x = dI;
#pragma unroll
    for (int d = 1; d < 64; d <<= 1) {
        int y = __shfl_up(x, d, 64);
        if (lane >= d) x += y;
    }
    if (lane == 63) wsum[wv] = x;
    const int bucket = dI > 63 ? 63 : dI;
    atomicAdd(&bcnt[bucket], 1);
    __syncthreads();

    // 4. combine wave sums; bucket-offset scan (wave 0)
    {
        int prefix = 0;
#pragma unroll
        for (int w = 0; w < 3; ++w) if (w < wv) prefix += wsum[w];
        int incl = x + prefix;
        scanA[t]  = incl;
        cursor[t] = incl - dI;
    }
    if (t < 64) {
        int c = bcnt[t], xx = c;
#pragma unroll
        for (int d = 1; d < 64; d <<= 1) {
            int y = __shfl_up(xx, d, 64);
            if (lane >= d) xx += y;
        }
        boff[t] = xx - c;   // exclusive
    }
    __syncthreads();

    // 5. degree-sorted perm scatter + edge scatter (f16 norm pack)
    { int pos = atomicAdd(&boff[bucket], 1); perm[pos] = t; }
#pragma unroll
    for (int i = 0; i < EPT_; ++i) {
        int s = sB[i], dd = dB[i];
        int pos = atomicAdd(&cursor[dd], 1);
        float nrm = inv_o[s] * inv_i[dd];
        unsigned short h = __half_as_ushort(__float2half(nrm));
        packedE[pos] = ((unsigned int)s << 16) | (unsigned int)h;
    }
    __syncthreads();

    // 6. node assignment into registers; then overlay is dead
    const int node = perm[t];
    const int end  = scanA[node];
    const int beg  = end - deg_i[node];
    __syncthreads();

    // ---- stage node features for BOTH batches as f16 (cols 6,7 zero-pad) ----
    {
        const float* gA = gf + (size_t)b0 * (N_ * FIN_);
        const float* gB = gA + N_ * FIN_;
        for (int i = t; i < N_ * 8; i += 256) {
            int n = i >> 3, k = i & 7;
            hbuf[0][n * HSTR_ + k] = __float2half((k < FIN_) ? gA[n * FIN_ + k] : 0.f);
            hbuf[1][n * HSTR_ + k] = __float2half((k < FIN_) ? gB[n * FIN_ + k] : 0.f);
        }
    }
    __syncthreads();

    const __half2 z2 = __float2half2_rn(0.f);

    // ---- layer 1: f16 gather (both batches) + f32 [6x32] GEMM + relu ----
    {
        __half2 aA[4] = {z2, z2, z2, z2};
        __half2 aB[4] = {z2, z2, z2, z2};
        for (int e = beg; e < end; ++e) {
            unsigned int u = packedE[e];
            __half2 w2 = __half2half2(__ushort_as_half((unsigned short)(u & 0xffffu)));
            int ro = (u >> 16) * HSTR_;
            union { float4 f4; __half2 h2[4]; } rA, rB;
            rA.f4 = *(const float4*)&hbuf[0][ro];
            rB.f4 = *(const float4*)&hbuf[1][ro];
#pragma unroll
            for (int q = 0; q < 4; ++q) {
                aA[q] = __hfma2(w2, rA.h2[q], aA[q]);
                aB[q] = __hfma2(w2, rB.h2[q], aB[q]);
            }
        }
        float oA[32], oB[32];
#pragma unroll
        for (int j = 0; j < 32; ++j) { float bj = b1[j]; oA[j] = bj; oB[j] = bj; }
#pragma unroll
        for (int k = 0; k < FIN_; ++k) {
            float akA = (k & 1) ? __high2float(aA[k >> 1]) : __low2float(aA[k >> 1]);
            float akB = (k & 1) ? __high2float(aB[k >> 1]) : __low2float(aB[k >> 1]);
            const float* wr = &W1[k * 32];
#pragma unroll
            for (int j = 0; j < 32; ++j) { float w = wr[j]; oA[j] += akA * w; oB[j] += akB * w; }
        }
        __syncthreads();
        union { float4 f4; __half2 h2[4]; } w;
        float4* rowA = (float4*)&hbuf[0][node * HSTR_];
        float4* rowB = (float4*)&hbuf[1][node * HSTR_];
#pragma unroll
        for (int q = 0; q < 4; ++q) {
#pragma unroll
            for (int r = 0; r < 4; ++r)
                w.h2[r] = __floats2half2_rn(fmaxf(oA[8*q + 2*r], 0.f), fmaxf(oA[8*q + 2*r + 1], 0.f));
            rowA[q] = w.f4;
#pragma unroll
            for (int r = 0; r < 4; ++r)
                w.h2[r] = __floats2half2_rn(fmaxf(oB[8*q + 2*r], 0.f), fmaxf(oB[8*q + 2*r + 1], 0.f));
            rowB[q] = w.f4;
        }
    }
    __syncthreads();

    // ---- layers 2 & 3: f16 gather (both batches) + MFMA 16x16x32 GEMM ----
    const int m16  = lane & 15;       // MFMA row/col-within-16
    const int q4   = lane >> 4;       // quad index 0..3
    const int slab = wv * 64;         // this wave's private 64-node slab

    for (int L = 0; L < 2; ++L) {
        const float* Wl = (L == 0) ? W2 : W3;
        const float* Bl = (L == 0) ? b2 : b3;

        // prefetch B fragments + bias (batch-invariant; overlaps gather below)
        half8 bfrag[2];
        float bias_c[2];
#pragma unroll
        for (int h = 0; h < 2; ++h) {
            int col = m16 + 16 * h;
#pragma unroll
            for (int j = 0; j < 8; ++j)
                bfrag[h][j] = (_Float16)Wl[(q4 * 8 + j) * 32 + col];
            bias_c[h] = Bl[col];
        }

        // gather: acc = sum_e w * h[src], both batches per edge decode
        __half2 accA[16], accB[16];
#pragma unroll
        for (int j = 0; j < 16; ++j) { accA[j] = z2; accB[j] = z2; }
        for (int e = beg; e < end; ++e) {
            unsigned int u = packedE[e];
            __half2 w2 = __half2half2(__ushort_as_half((unsigned short)(u & 0xffffu)));
            int ro = (u >> 16) * HSTR_;
            const float4* hrA = (const float4*)&hbuf[0][ro];
            const float4* hrB = (const float4*)&hbuf[1][ro];
            union { float4 f4; __half2 h2[4]; } r0, r1, r2, r3;
            r0.f4 = hrA[0]; r1.f4 = hrA[1]; r2.f4 = hrA[2]; r3.f4 = hrA[3];
#pragma unroll
            for (int q = 0; q < 4; ++q) {
                accA[q]      = __hfma2(w2, r0.h2[q], accA[q]);
                accA[4 + q]  = __hfma2(w2, r1.h2[q], accA[4 + q]);
                accA[8 + q]  = __hfma2(w2, r2.h2[q], accA[8 + q]);
                accA[12 + q] = __hfma2(w2, r3.h2[q], accA[12 + q]);
            }
            r0.f4 = hrB[0]; r1.f4 = hrB[1]; r2.f4 = hrB[2]; r3.f4 = hrB[3];
#pragma unroll
            for (int q = 0; q < 4; ++q) {
                accB[q]      = __hfma2(w2, r0.h2[q], accB[q]);
                accB[4 + q]  = __hfma2(w2, r1.h2[q], accB[4 + q]);
                accB[8 + q]  = __hfma2(w2, r2.h2[q], accB[8 + q]);
                accB[12 + q] = __hfma2(w2, r3.h2[q], accB[12 + q]);
            }
        }
        __syncthreads();                     // all gather reads of h done
        {
            // stage agg rows into hbuf (h is dead now)
            union { float4 f4; __half2 h2[4]; } w;
            float4* rowA = (float4*)&hbuf[0][node * HSTR_];
            float4* rowB = (float4*)&hbuf[1][node * HSTR_];
#pragma unroll
            for (int q = 0; q < 4; ++q) {
#pragma unroll
                for (int r = 0; r < 4; ++r) w.h2[r] = accA[4 * q + r];
                rowA[q] = w.f4;
#pragma unroll
                for (int r = 0; r < 4; ++r) w.h2[r] = accB[4 * q + r];
                rowB[q] = w.f4;
            }
        }
        __syncthreads();                     // agg visible to all

        // MFMA: wave processes its own 64-node slab, both batches
#pragma unroll
        for (int bb = 0; bb < BPB_; ++bb) {
            half8 afrag[4];
#pragma unroll
            for (int g = 0; g < 4; ++g) {
                union { float4 f4; half8 h8; } u;
                u.f4 = *(const float4*)&hbuf[bb][(slab + g * 16 + m16) * HSTR_ + q4 * 8];
                afrag[g] = u.h8;
            }
            f32x4 D[4][2];
#pragma unroll
            for (int g = 0; g < 4; ++g) {
#pragma unroll
                for (int h = 0; h < 2; ++h) {
                    f32x4 c = {bias_c[h], bias_c[h], bias_c[h], bias_c[h]};
                    D[g][h] = __builtin_amdgcn_mfma_f32_16x16x32_f16(afrag[g], bfrag[h], c, 0, 0, 0);
                }
            }
            // relu + writeback: D row = q4*4 + r, col = h*16+m16 (wave-private slab)
#pragma unroll
            for (int g = 0; g < 4; ++g) {
#pragma unroll
                for (int h = 0; h < 2; ++h) {
#pragma unroll
                    for (int r = 0; r < 4; ++r) {
                        float v = fmaxf(D[g][h][r], 0.f);
                        hbuf[bb][(slab + g * 16 + q4 * 4 + r) * HSTR_ + h * 16 + m16] = __float2half(v);
                    }
                }
            }
        }
        __syncthreads();
    }

    // ---- mean over nodes -> hg[32] per batch (f32) ----
    {
        int j = t & 31, g8 = t >> 5;
        float sA = 0.f, sB = 0.f;
        for (int i = 0; i < 32; ++i) {
            int ro = (g8 * 32 + i) * HSTR_ + j;
            sA += __half2float(hbuf[0][ro]);
            sB += __half2float(hbuf[1][ro]);
        }
        part[0][g8 * 33 + j] = sA;
        part[1][g8 * 33 + j] = sB;
    }
    __syncthreads();
    if (t < 64) {
        int bb = t >> 5, j = t & 31;
        float sum = 0.f;
#pragma unroll
        for (int g8 = 0; g8 < 8; ++g8) sum += part[bb][g8 * 33 + j];
        hgl[bb][j] = sum * (1.0f / 256.0f);
    }
    if (t < BPB_ * VEC_) {                   // vec -> comb low 26, both batches
        int bb = t / VEC_, j = t - bb * VEC_;
        combS[bb][j] = vec[(b0 + bb) * VEC_ + j];
    }
    __syncthreads();

    // ---- emb (f32): comb[26..58) ----
    if (t < 64) {
        int bb = t >> 5, j = t & 31;
        float v = be[j];
#pragma unroll
        for (int k = 0; k < 32; ++k) v += hgl[bb][k] * We[k * 32 + j];
        combS[bb][VEC_ + j] = v;
    }
    __syncthreads();

    // ---- head: thread t -> pi/vf outputs 2t, 2t+1, both batches ----
    {
        const float2 bp = ((const float2*)bpi)[t];
        const float2 bv = ((const float2*)bvf)[t];
        float2 aP0 = bp, aP1 = bp, aV0 = bv, aV1 = bv;
        const float2* Wp = (const float2*)Wpi;   // [58][256] float2
        const float2* Wv = (const float2*)Wvf;
        for (int k = 0; k < VEC_ + 32; ++k) {
            float2 a = Wp[k * 256 + t];
            float2 d = Wv[k * 256 + t];
            float c0 = combS[0][k];              // uniform addr -> LDS broadcast
            float c1 = combS[1][k];
            aP0.x += c0 * a.x; aP0.y += c0 * a.y;
            aP1.x += c1 * a.x; aP1.y += c1 * a.y;
            aV0.x += c0 * d.x; aV0.y += c0 * d.y;
            aV1.x += c1 * d.x; aV1.y += c1 * d.y;
        }
        out[b0 * 256 + t]                = make_float2(fmaxf(aP0.x, 0.f), fmaxf(aP0.y, 0.f));
        out[(b0 + 1) * 256 + t]          = make_float2(fmaxf(aP1.x, 0.f), fmaxf(aP1.y, 0.f));
        out[262144 + b0 * 256 + t]       = make_float2(fmaxf(aV0.x, 0.f), fmaxf(aV0.y, 0.f));
        out[262144 + (b0 + 1) * 256 + t] = make_float2(fmaxf(aV1.x, 0.f), fmaxf(aV1.y, 0.f));
    }
}

extern "C" void kernel_launch(void* const* d_in, const int* in_sizes, int n_in,
                              void* d_out, int out_size, void* d_ws, size_t ws_size,
                              hipStream_t stream)
{
    // d_in order: 0 gf, 1 vec, 2 src, 3 dst, 4 W1, 5 b1, 6 W2, 7 b2, 8 W3, 9 b3,
    //             10 W_emb, 11 b_emb, 12 W_pi, 13 b_pi, 14 W_vf, 15 b_vf
    fused_kernel<<<B_ / BPB_, 256, 0, stream>>>(
        (const float*)d_in[0], (const float*)d_in[1],
        (const int*)d_in[2], (const int*)d_in[3],
        (const float*)d_in[4], (const float*)d_in[5],
        (const float*)d_in[6], (const float*)d_in[7],
        (const float*)d_in[8], (const float*)d_in[9],
        (const float*)d_in[10], (const float*)d_in[11],
        (const float*)d_in[12], (const float*)d_in[13],
        (const float*)d_in[14], (const float*)d_in[15],
        (float2*)d_out);
}

// Round 9
// 114.872 us; speedup vs baseline: 1.0419x; 1.0243x over previous
//
#include <hip/hip_runtime.h>
#include <hip/hip_fp16.h>

// Problem constants (from reference) — ALL TENSORS ARE FLOAT32.
#define B_    1024
#define N_    256
#define E_    2304      // == 9 * 256 exactly
#define EPT_  9         // edges per thread in CSR build
#define FIN_  6
#define VEC_  26
#define HSTR_ 40        // f16 LDS row stride (80 B, 16B-aligned)
#define BPB_  2         // batches per block

typedef _Float16 half8 __attribute__((ext_vector_type(8)));
typedef float    f32x4 __attribute__((ext_vector_type(4)));

// ---------------------------------------------------------------------------
// 512 blocks x 512 threads. Thread (u = t&255, bh = t>>8): u = node slot,
// bh = batch half. This is the round-3 kernel (tripwire-green twice, 117.5us)
// with the two batches SPLIT ACROSS THREAD HALVES instead of interleaved in
// one thread: every per-batch instruction sequence (CSR scatter, gather
// order, dense GEMM order, MFMA, mean, head) is IDENTICAL to round 3, so
// outputs are bit-identical to the passing kernel. Serial phase lengths
// halve; waves/block 4->8; occupancy cap doubles. CSR build runs on t<256
// only (byte-identical code, the empirically deterministic lineage);
// plain __launch_bounds__(512) (the (256,2)-style min-waves form is the one
// attribute shared by all three tripwire-failing rounds — avoided).
// ---------------------------------------------------------------------------
__global__ __launch_bounds__(512) void fused_kernel(
    const float* __restrict__ gf,    // [B,N,6]
    const float* __restrict__ vec,   // [B,26]
    const int* __restrict__ src, const int* __restrict__ dst,
    const float* __restrict__ W1, const float* __restrict__ b1,   // [6,32],[32]
    const float* __restrict__ W2, const float* __restrict__ b2,   // [32,32]
    const float* __restrict__ W3, const float* __restrict__ b3,
    const float* __restrict__ We, const float* __restrict__ be,   // [32,32]
    const float* __restrict__ Wpi, const float* __restrict__ bpi, // [58,512],[512]
    const float* __restrict__ Wvf, const float* __restrict__ bvf,
    float2* __restrict__ out)        // f32 pairs; pi @ [0,262144), vf @ +262144
{
    __shared__ __align__(16) __half hbuf[BPB_][N_ * HSTR_];  // 40,960 B
    __shared__ unsigned int packedE[E_];                     //  9,216 B
    __shared__ float part[BPB_][8 * 33];
    __shared__ float hgl[BPB_][32];
    __shared__ float combS[BPB_][64];
    __shared__ int   wsum[4];

    const int t  = threadIdx.x;
    const int u  = t & 255;          // node slot
    const int bh = t >> 8;           // batch half (0 or 1)
    const int b0 = blockIdx.x * BPB_;
    const int lane = t & 63, wv = t >> 6;   // wv 0..7

    // ---- CSR scratch overlaid on hbuf[0] (consumed before feature staging) ----
    int*   deg_o  = (int*)&hbuf[0][0];          // [256]
    int*   deg_i  = (int*)&hbuf[0][0] + 256;    // [256]
    int*   scanA  = (int*)&hbuf[0][0] + 512;    // [256]
    int*   cursor = (int*)&hbuf[0][0] + 768;    // [256]
    int*   perm   = (int*)&hbuf[0][0] + 1024;   // [256]
    float* inv_o  = (float*)&hbuf[0][0] + 1280; // [256]
    float* inv_i  = (float*)&hbuf[0][0] + 1536; // [256]
    int*   bcnt   = (int*)&hbuf[0][0] + 1792;   // [64]
    int*   boff   = (int*)&hbuf[0][0] + 1856;   // [64]

    // ==================== CSR build: t<256 only (round-3 verbatim) =========
    // 1. zero counters
    if (t < 256) {
        deg_o[t] = 0; deg_i[t] = 0;
        if (t < 64) bcnt[t] = 0;
    }
    __syncthreads();

    // 2. load edges, count degrees
    int sB[EPT_], dB[EPT_];
    if (t < 256) {
#pragma unroll
        for (int i = 0; i < EPT_; ++i) { int e = t + 256 * i; sB[i] = src[e]; dB[i] = dst[e]; }
#pragma unroll
        for (int i = 0; i < EPT_; ++i) { atomicAdd(&deg_o[sB[i]], 1); atomicAdd(&deg_i[dB[i]], 1); }
    }
    __syncthreads();

    // 3. inv factors + wave-level scan of deg_i + bucket counts
    int x = 0, dI = 0, bucket = 0;
    if (t < 256) {
        dI = deg_i[t];
        {
            int dO = deg_o[t];
            inv_o[t] = dO > 0 ? rsqrtf((float)dO) : 0.f;
            inv_i[t] = dI > 0 ? rsqrtf((float)dI) : 0.f;
        }
        x = dI;
#pragma unroll
        for (int d = 1; d < 64; d <<= 1) {
            int y = __shfl_up(x, d, 64);
            if (lane >= d) x += y;
        }
        if (lane == 63) wsum[wv] = x;
        bucket = dI > 63 ? 63 : dI;
        atomicAdd(&bcnt[bucket], 1);
    }
    __syncthreads();

    // 4. combine wave sums; bucket-offset scan
    if (t < 256) {
        int prefix = 0;
#pragma unroll
        for (int w = 0; w < 3; ++w) if (w < wv) prefix += wsum[w];
        int incl = x + prefix;
        scanA[t]  = incl;
        cursor[t] = incl - dI;
    }
    if (t < 64) {
        int c = bcnt[t], xx = c;
#pragma unroll
        for (int d = 1; d < 64; d <<= 1) {
            int y = __shfl_up(xx, d, 64);
            if (lane >= d) xx += y;
        }
        boff[t] = xx - c;   // exclusive
    }
    __syncthreads();

    // 5. degree-sorted perm scatter + edge scatter (f16 norm pack)
    if (t < 256) {
        { int pos = atomicAdd(&boff[bucket], 1); perm[pos] = t; }
#pragma unroll
        for (int i = 0; i < EPT_; ++i) {
            int s = sB[i], dd = dB[i];
            int pos = atomicAdd(&cursor[dd], 1);
            float nrm = inv_o[s] * inv_i[dd];
            unsigned short hh = __half_as_ushort(__float2half(nrm));
            packedE[pos] = ((unsigned int)s << 16) | (unsigned int)hh;
        }
    }
    __syncthreads();

    // 6. node assignment into registers (ALL 512 threads); then overlay dead
    const int node = perm[u];
    const int end  = scanA[node];
    const int beg  = end - deg_i[node];
    __syncthreads();

    // ---- stage node features: half bh stages batch bh (cols 6,7 zero-pad) ----
    {
        const float* g = gf + (size_t)(b0 + bh) * (N_ * FIN_);
        for (int i = u; i < N_ * 8; i += 256) {
            int n = i >> 3, k = i & 7;
            hbuf[bh][n * HSTR_ + k] = __float2half((k < FIN_) ? g[n * FIN_ + k] : 0.f);
        }
    }
    __syncthreads();

    const __half2 z2 = __float2half2_rn(0.f);

    // ---- layer 1: f16 gather (own batch) + f32 [6x32] GEMM + relu ----
    {
        __half2 a2[4] = {z2, z2, z2, z2};
        for (int e = beg; e < end; ++e) {
            unsigned int uu = packedE[e];
            __half2 w2 = __half2half2(__ushort_as_half((unsigned short)(uu & 0xffffu)));
            int ro = (uu >> 16) * HSTR_;
            union { float4 f4; __half2 h2[4]; } r;
            r.f4 = *(const float4*)&hbuf[bh][ro];
#pragma unroll
            for (int q = 0; q < 4; ++q) a2[q] = __hfma2(w2, r.h2[q], a2[q]);
        }
        float o[32];
#pragma unroll
        for (int j = 0; j < 32; ++j) o[j] = b1[j];
#pragma unroll
        for (int k = 0; k < FIN_; ++k) {
            float ak = (k & 1) ? __high2float(a2[k >> 1]) : __low2float(a2[k >> 1]);
            const float* wr = &W1[k * 32];
#pragma unroll
            for (int j = 0; j < 32; ++j) o[j] += ak * wr[j];
        }
        __syncthreads();
        union { float4 f4; __half2 h2[4]; } w;
        float4* row = (float4*)&hbuf[bh][node * HSTR_];
#pragma unroll
        for (int q = 0; q < 4; ++q) {
#pragma unroll
            for (int r = 0; r < 4; ++r)
                w.h2[r] = __floats2half2_rn(fmaxf(o[8*q + 2*r], 0.f), fmaxf(o[8*q + 2*r + 1], 0.f));
            row[q] = w.f4;
        }
    }
    __syncthreads();

    // ---- layers 2 & 3: f16 gather (own batch) + MFMA 16x16x32 GEMM ----
    const int m16  = lane & 15;       // MFMA row/col-within-16
    const int q4   = lane >> 4;       // quad index 0..3
    const int slab = (wv & 3) * 64;   // wave's 64-node slab within its batch
    const int wb   = wv >> 2;         // which batch this wave MFMAs

    for (int L = 0; L < 2; ++L) {
        const float* Wl = (L == 0) ? W2 : W3;
        const float* Bl = (L == 0) ? b2 : b3;

        // prefetch B fragments + bias (batch-invariant; overlaps gather below)
        half8 bfrag[2];
        float bias_c[2];
#pragma unroll
        for (int cb = 0; cb < 2; ++cb) {
            int col = m16 + 16 * cb;
#pragma unroll
            for (int j = 0; j < 8; ++j)
                bfrag[cb][j] = (_Float16)Wl[(q4 * 8 + j) * 32 + col];
            bias_c[cb] = Bl[col];
        }

        // gather: acc = sum_e w * h[src], own batch only (round-3 order)
        __half2 acc2[16];
#pragma unroll
        for (int j = 0; j < 16; ++j) acc2[j] = z2;
        for (int e = beg; e < end; ++e) {
            unsigned int uu = packedE[e];
            __half2 w2 = __half2half2(__ushort_as_half((unsigned short)(uu & 0xffffu)));
            int ro = (uu >> 16) * HSTR_;
            const float4* hr = (const float4*)&hbuf[bh][ro];
            union { float4 f4; __half2 h2[4]; } r0, r1, r2, r3;
            r0.f4 = hr[0]; r1.f4 = hr[1]; r2.f4 = hr[2]; r3.f4 = hr[3];
#pragma unroll
            for (int q = 0; q < 4; ++q) {
                acc2[q]      = __hfma2(w2, r0.h2[q], acc2[q]);
                acc2[4 + q]  = __hfma2(w2, r1.h2[q], acc2[4 + q]);
                acc2[8 + q]  = __hfma2(w2, r2.h2[q], acc2[8 + q]);
                acc2[12 + q] = __hfma2(w2, r3.h2[q], acc2[12 + q]);
            }
        }
        __syncthreads();                     // all gather reads of h done
        {
            // stage agg row into hbuf (h is dead now)
            union { float4 f4; __half2 h2[4]; } w;
            float4* row = (float4*)&hbuf[bh][node * HSTR_];
#pragma unroll
            for (int q = 0; q < 4; ++q) {
#pragma unroll
                for (int r = 0; r < 4; ++r) w.h2[r] = acc2[4 * q + r];
                row[q] = w.f4;
            }
        }
        __syncthreads();                     // agg visible to all

        // MFMA: wave wv handles slab (wv&3)*64 of batch wv>>2
        {
            half8 afrag[4];
#pragma unroll
            for (int g = 0; g < 4; ++g) {
                union { float4 f4; half8 h8; } uf;
                uf.f4 = *(const float4*)&hbuf[wb][(slab + g * 16 + m16) * HSTR_ + q4 * 8];
                afrag[g] = uf.h8;
            }
            f32x4 D[4][2];
#pragma unroll
            for (int g = 0; g < 4; ++g) {
#pragma unroll
                for (int cb = 0; cb < 2; ++cb) {
                    f32x4 c = {bias_c[cb], bias_c[cb], bias_c[cb], bias_c[cb]};
                    D[g][cb] = __builtin_amdgcn_mfma_f32_16x16x32_f16(afrag[g], bfrag[cb], c, 0, 0, 0);
                }
            }
            // relu + writeback: D row = q4*4 + r, col = cb*16+m16
#pragma unroll
            for (int g = 0; g < 4; ++g) {
#pragma unroll
                for (int cb = 0; cb < 2; ++cb) {
#pragma unroll
                    for (int r = 0; r < 4; ++r) {
                        float v = fmaxf(D[g][cb][r], 0.f);
                        hbuf[wb][(slab + g * 16 + q4 * 4 + r) * HSTR_ + cb * 16 + m16] = __float2half(v);
                    }
                }
            }
        }
        __syncthreads();
    }

    // ---- mean over nodes -> hg[32] per batch (f32; round-3 order per batch) ----
    {
        int j = u & 31, g8 = u >> 5;
        float s = 0.f;
        for (int i = 0; i < 32; ++i)
            s += __half2float(hbuf[bh][(g8 * 32 + i) * HSTR_ + j]);
        part[bh][g8 * 33 + j] = s;
    }
    __syncthreads();
    if (t < 64) {
        int bb = t >> 5, j = t & 31;
        float sum = 0.f;
#pragma unroll
        for (int g8 = 0; g8 < 8; ++g8) sum += part[bb][g8 * 33 + j];
        hgl[bb][j] = sum * (1.0f / 256.0f);
    }
    if (t < BPB_ * VEC_) {                   // vec -> comb low 26, both batches
        int bb = t / VEC_, j = t - bb * VEC_;
        combS[bb][j] = vec[(b0 + bb) * VEC_ + j];
    }
    __syncthreads();

    // ---- emb (f32): comb[26..58) ----
    if (t < 64) {
        int bb = t >> 5, j = t & 31;
        float v = be[j];
#pragma unroll
        for (int k = 0; k < 32; ++k) v += hgl[bb][k] * We[k * 32 + j];
        combS[bb][VEC_ + j] = v;
    }
    __syncthreads();

    // ---- head: half 0 -> pi (both batches), half 1 -> vf (both batches) ----
    {
        const float* Wm = (bh == 0) ? Wpi : Wvf;
        const float* bm = (bh == 0) ? bpi : bvf;
        const float2 bp = ((const float2*)bm)[u];
        float2 a0 = bp, a1 = bp;
        const float2* Wr = (const float2*)Wm;    // [58][256] float2
        for (int k = 0; k < VEC_ + 32; ++k) {
            float2 a = Wr[k * 256 + u];
            float c0 = combS[0][k];              // uniform addr -> LDS broadcast
            float c1 = combS[1][k];
            a0.x += c0 * a.x; a0.y += c0 * a.y;
            a1.x += c1 * a.x; a1.y += c1 * a.y;
        }
        int base = bh * 262144;
        out[base + b0 * 256 + u]       = make_float2(fmaxf(a0.x, 0.f), fmaxf(a0.y, 0.f));
        out[base + (b0 + 1) * 256 + u] = make_float2(fmaxf(a1.x, 0.f), fmaxf(a1.y, 0.f));
    }
}

extern "C" void kernel_launch(void* const* d_in, const int* in_sizes, int n_in,
                              void* d_out, int out_size, void* d_ws, size_t ws_size,
                              hipStream_t stream)
{
    // d_in order: 0 gf, 1 vec, 2 src, 3 dst, 4 W1, 5 b1, 6 W2, 7 b2, 8 W3, 9 b3,
    //             10 W_emb, 11 b_emb, 12 W_pi, 13 b_pi, 14 W_vf, 15 b_vf
    fused_kernel<<<B_ / BPB_, 512, 0, stream>>>(
        (const float*)d_in[0], (const float*)d_in[1],
        (const int*)d_in[2], (const int*)d_in[3],
        (const float*)d_in[4], (const float*)d_in[5],
        (const float*)d_in[6], (const float*)d_in[7],
        (const float*)d_in[8], (const float*)d_in[9],
        (const float*)d_in[10], (const float*)d_in[11],
        (const float*)d_in[12], (const float*)d_in[13],
        (const float*)d_in[14], (const float*)d_in[15],
        (float2*)d_out);
}